// Round 2
// baseline (180.738 us; speedup 1.0000x reference)
//
#include <hip/hip_runtime.h>
#include <hip/hip_bf16.h>

#define EPS 1e-5f
#define NPTS 262144
#define NB 16

typedef __attribute__((ext_vector_type(8))) short bf16x8;
typedef __attribute__((ext_vector_type(4))) float f32x4;

// ws float offsets
#define WS_MOM  0      // 9 floats: Sf0,Sf1,Sf2,S00,S01,S02,S11,S12,S22 (atomicAdd, zeroed)
#define WS_MAXU 16     // 2048 u32 orderable max  (zeroed)
#define WS_NEGU 2064   // 2048 u32 orderable max of -v (zeroed)
#define WS_E    4112   // E'0[64],E'1[64],E'2[64]
#define WS_T    4304   // T''[16][64]
#define WS_W3   5328   // 2048 u32 = 4096 bf16 (W3 row-major [64][64])
#define WS_SCRA 7376   // scratchA[256][64]  ([16 batches][f0,f1,f2,cnt] per block)

__device__ inline float decodeu(unsigned u){
  unsigned bits = (u & 0x80000000u) ? (u ^ 0x80000000u) : ~u;
  return __uint_as_float(bits);
}
__device__ inline unsigned f2bf(float f){
  unsigned u = __float_as_uint(f);
  return (u + 0x7FFFu + ((u>>16)&1u)) >> 16;
}
__device__ inline unsigned pack2bf(float lo, float hi){
  return (f2bf(hi)<<16) | (f2bf(lo) & 0xFFFFu);
}

// ---------------- kernel A: global + per-batch moments of feats ----------------
__global__ __launch_bounds__(256) void kA(const float* __restrict__ feats,
                                          const int* __restrict__ bidx,
                                          float* __restrict__ wsf) {
  __shared__ float hist[NB*4];
  __shared__ float red[4*9];
  int tid = threadIdx.x;
  if (tid < NB*4) hist[tid] = 0.f;
  __syncthreads();
  float a0=0,a1=0,a2=0,a3=0,a4=0,a5=0,a6=0,a7=0,a8=0;
  for (int p = blockIdx.x*256 + tid; p < NPTS; p += 256*256) {
    float f0 = feats[3*p], f1 = feats[3*p+1], f2 = feats[3*p+2];
    int b = bidx[p];
    a0+=f0; a1+=f1; a2+=f2;
    a3+=f0*f0; a4+=f0*f1; a5+=f0*f2; a6+=f1*f1; a7+=f1*f2; a8+=f2*f2;
    atomicAdd(&hist[b*4+0], f0);
    atomicAdd(&hist[b*4+1], f1);
    atomicAdd(&hist[b*4+2], f2);
    atomicAdd(&hist[b*4+3], 1.0f);
  }
  float acc[9] = {a0,a1,a2,a3,a4,a5,a6,a7,a8};
  int lane = tid & 63, wv = tid >> 6;
  #pragma unroll
  for (int k=0;k<9;k++){
    float v = acc[k];
    v += __shfl_down(v,32); v += __shfl_down(v,16); v += __shfl_down(v,8);
    v += __shfl_down(v,4);  v += __shfl_down(v,2);  v += __shfl_down(v,1);
    if (lane==0) red[wv*9+k] = v;
  }
  __syncthreads();
  if (tid < 9) atomicAdd(&wsf[WS_MOM+tid], red[tid]+red[9+tid]+red[18+tid]+red[27+tid]);
  if (tid < 64) wsf[WS_SCRA + blockIdx.x*64 + tid] = hist[tid];
}

// ---------------- kernel C: raw per-batch seg max & min of feats@W1.T ----------------
__global__ __launch_bounds__(256) void kC(const float* __restrict__ feats,
                                          const int* __restrict__ bidx,
                                          const float* __restrict__ W1,
                                          float* __restrict__ wsf) {
  unsigned* maxu = (unsigned*)wsf + WS_MAXU;
  unsigned* negu = (unsigned*)wsf + WS_NEGU;
  __shared__ unsigned lmax[NB*128];
  __shared__ unsigned lneg[NB*128];
  int tid = threadIdx.x;
  int c = tid & 127, grp = tid >> 7;
  for (int i = tid; i < NB*128; i += 256) { lmax[i]=0u; lneg[i]=0u; }
  float w0=W1[3*c], w1=W1[3*c+1], w2=W1[3*c+2];
  __syncthreads();
  int base = blockIdx.x*256 + grp*128;
  for (int k=0;k<128;k++){
    int p = base + k;
    float f0=feats[3*p], f1=feats[3*p+1], f2=feats[3*p+2];
    int b = bidx[p];
    float v = fmaf(f2,w2,fmaf(f1,w1,f0*w0));
    unsigned bits = __float_as_uint(v);
    unsigned u  = (bits & 0x80000000u) ? ~bits : (bits|0x80000000u);
    unsigned nb = bits ^ 0x80000000u;
    unsigned un = (nb & 0x80000000u) ? ~nb : (nb|0x80000000u);
    atomicMax(&lmax[b*128+c], u);
    atomicMax(&lneg[b*128+c], un);
  }
  __syncthreads();
  for (int i=tid;i<NB*128;i+=256){
    unsigned v = lmax[i]; if (v > maxu[i]) atomicMax(&maxu[i], v);
    unsigned w = lneg[i]; if (w > negu[i]) atomicMax(&negu[i], w);
  }
}

// ---------------- kernel B: all tiny math (single block) ----------------
__global__ __launch_bounds__(256) void kB(float* __restrict__ wsf,
    const float* __restrict__ W1, const float* __restrict__ g1, const float* __restrict__ b1,
    const float* __restrict__ W2, const float* __restrict__ g2, const float* __restrict__ b2,
    const float* __restrict__ W3) {
  __shared__ float s_sc[128], s_sh[128], s_smbn[NB*128], sE[3*64], sg[64], sT[NB*64];
  __shared__ float sb[64], sm[9], s_s2[64], s_t2[64], spart[256];
  int tid = threadIdx.x;
  // reduce per-batch scratch (256 blocks x 64)
  { int q = tid>>6, cc = tid&63; float s=0;
    for (int i=q;i<256;i+=4) s += wsf[WS_SCRA + i*64 + cc];
    spart[q*64+cc]=s; }
  if (tid < 9) sm[tid] = wsf[WS_MOM + tid];
  __syncthreads();
  if (tid < 64) sb[tid] = spart[tid]+spart[64+tid]+spart[128+tid]+spart[192+tid];
  const float invN = 1.0f/NPTS;
  if (tid < 128){
    int c=tid; float w0=W1[3*c],w1=W1[3*c+1],w2=W1[3*c+2];
    float mean = (w0*sm[0]+w1*sm[1]+w2*sm[2])*invN;
    float ex2 = (w0*w0*sm[3]+w1*w1*sm[6]+w2*w2*sm[8]
               + 2.f*(w0*w1*sm[4]+w0*w2*sm[5]+w1*w2*sm[7]))*invN;
    float var = ex2 - mean*mean;
    float sc = g1[c]*rsqrtf(var+EPS);
    s_sc[c]=sc; s_sh[c]=b1[c]-mean*sc;
  }
  __syncthreads();
  { const unsigned* maxu = (const unsigned*)wsf + WS_MAXU;
    const unsigned* negu = (const unsigned*)wsf + WS_NEGU;
    for (int i=tid;i<NB*128;i+=256){
      int c=i&127;
      float mx = decodeu(maxu[i]);
      float mn = -decodeu(negu[i]);
      float sc = s_sc[c];
      s_smbn[i] = sc*((sc>=0.f)?mx:mn) + s_sh[c];
    } }
  __syncthreads();
  { int c = tid & 63, which = tid >> 6;
    float s=0;
    for (int j=0;j<128;j++){
      float m = (which<3) ? s_sc[j]*W1[3*j+which] : s_sh[j];
      s += W2[c*256+j]*m;
    }
    if (which<3) sE[which*64+c]=s; else sg[c]=s; }
  __syncthreads();
  for (int i=tid;i<NB*64;i+=256){
    int b=i>>6, c=i&63; float s=0;
    for (int j=0;j<128;j++) s += W2[c*256+128+j]*s_smbn[b*128+j];
    sT[i]=s;
  }
  __syncthreads();
  if (tid < 64){
    int c=tid;
    float e0=sE[c],e1=sE[64+c],e2=sE[128+c],gc=sg[c];
    float eS1 = e0*sm[0]+e1*sm[1]+e2*sm[2];
    float eS2e = e0*e0*sm[3]+e1*e1*sm[6]+e2*e2*sm[8]
               + 2.f*(e0*e1*sm[4]+e0*e2*sm[5]+e1*e2*sm[7]);
    float sumY = eS1, sumYY = eS2e;
    #pragma unroll
    for (int b=0;b<NB;b++){
      float nb = sb[b*4+3];
      float hb = gc + sT[b*64+c];
      float eS1b = e0*sb[b*4]+e1*sb[b*4+1]+e2*sb[b*4+2];
      sumY += nb*hb;
      sumYY += 2.f*hb*eS1b + nb*hb*hb;
    }
    float mean2 = sumY*invN;
    float var2 = sumYY*invN - mean2*mean2;
    float s2 = g2[c]*rsqrtf(var2+EPS);
    float t2 = b2[c]-mean2*s2;
    s_s2[c]=s2; s_t2[c]=t2;
    wsf[WS_E + c] = e0*s2; wsf[WS_E+64+c]=e1*s2; wsf[WS_E+128+c]=e2*s2;
  }
  __syncthreads();
  for (int i=tid;i<NB*64;i+=256){
    int c=i&63;
    wsf[WS_T + i] = (sg[c]+sT[i])*s_s2[c] + s_t2[c];
  }
  { unsigned* w3u = (unsigned*)wsf + WS_W3;
    for (int i=tid;i<2048;i+=256){
      int k=i>>5, cp=i&31;
      w3u[i] = pack2bf(W3[k*64+2*cp], W3[k*64+2*cp+1]);
    } }
}

// ---------------- kernel F: fused y2 -> bn2/relu -> z@W3.T + b3 ----------------
__global__ __launch_bounds__(256) void kF(const float* __restrict__ feats,
                                          const int* __restrict__ bidx,
                                          const float* __restrict__ wsf,
                                          const float* __restrict__ b3,
                                          float* __restrict__ out) {
  __shared__ __align__(16) float Tl[NB*66];
  __shared__ __align__(16) unsigned zbuf[4*64*32];   // 4 waves x 64 rows x 128B
  int tid = threadIdx.x;
  for (int i=tid;i<NB*64;i+=256) Tl[(i>>6)*66 + (i&63)] = wsf[WS_T + i];
  int lane = tid & 63, wv = tid >> 6;
  int col = lane & 15, kgrp = lane >> 4;
  const ushort* w3b = (const ushort*)((const unsigned*)wsf + WS_W3);
  bf16x8 bfr[4][2];
  #pragma unroll
  for (int n=0;n<4;n++)
    #pragma unroll
    for (int kk=0;kk<2;kk++)
      bfr[n][kk] = *(const bf16x8*)(w3b + (n*16+col)*64 + kk*32 + kgrp*8);
  float bias[4];
  #pragma unroll
  for (int n=0;n<4;n++) bias[n] = b3[n*16+col];
  __syncthreads();
  const float* Eg = wsf + WS_E;
  int p0 = (blockIdx.x*4 + wv)*64;
  int p = p0 + lane;
  float f0 = feats[3*p], f1 = feats[3*p+1], f2 = feats[3*p+2];
  int b = bidx[p];
  const float* tb = &Tl[b*66];
  // phase 1: z = relu(E'.f + T''[b]) -> bf16 -> swizzled LDS
  unsigned rowbase = (unsigned)(wv*64+lane)*32;
  unsigned sw = (lane&7)<<2;
  #pragma unroll
  for (int j=0;j<8;j++){
    unsigned w[4];
    #pragma unroll
    for (int q=0;q<4;q++){
      int c = j*8 + q*2;
      float2 tp = *(const float2*)(tb + c);
      float y0 = fmaf(Eg[c],  f0, fmaf(Eg[64+c],  f1, fmaf(Eg[128+c],  f2, tp.x)));
      float y1 = fmaf(Eg[c+1],f0, fmaf(Eg[64+c+1],f1, fmaf(Eg[128+c+1],f2, tp.y)));
      float z0 = fmaxf(y0,0.f), z1 = fmaxf(y1,0.f);
      w[q] = pack2bf(z0, z1);
    }
    uint4 ch; ch.x=w[0]; ch.y=w[1]; ch.z=w[2]; ch.w=w[3];
    *(uint4*)&zbuf[rowbase + (((unsigned)(j*4)) ^ sw)] = ch;
  }
  __syncthreads();
  // phase 2: MFMA z[64x64] @ W3^T[64x64]
  bf16x8 af[4][2];
  #pragma unroll
  for (int m=0;m<4;m++){
    int row = m*16 + col;
    unsigned rb = (unsigned)(wv*64+row)*32;
    unsigned sw2 = (unsigned)(row&7)<<2;
    #pragma unroll
    for (int kk=0;kk<2;kk++){
      unsigned off = ((unsigned)(kk*16 + kgrp*4)) ^ sw2;
      af[m][kk] = *(const bf16x8*)&zbuf[rb + off];
    }
  }
  f32x4 acc[4][4];
  #pragma unroll
  for (int m=0;m<4;m++)
    #pragma unroll
    for (int n=0;n<4;n++)
      acc[m][n] = (f32x4){0.f,0.f,0.f,0.f};
  #pragma unroll
  for (int kk=0;kk<2;kk++)
    #pragma unroll
    for (int m=0;m<4;m++)
      #pragma unroll
      for (int n=0;n<4;n++)
        acc[m][n] = __builtin_amdgcn_mfma_f32_16x16x32_bf16(af[m][kk], bfr[n][kk], acc[m][n], 0,0,0);
  // epilogue: D row = pt (kgrp*4+r), col = out channel
  #pragma unroll
  for (int m=0;m<4;m++){
    int prow = p0 + m*16 + kgrp*4;
    #pragma unroll
    for (int n=0;n<4;n++){
      int cg = n*16+col;
      #pragma unroll
      for (int r=0;r<4;r++)
        out[(size_t)(prow+r)*64 + cg] = acc[m][n][r] + bias[n];
    }
  }
}

extern "C" void kernel_launch(void* const* d_in, const int* in_sizes, int n_in,
                              void* d_out, int out_size, void* d_ws, size_t ws_size,
                              hipStream_t stream) {
  const float* feats = (const float*)d_in[0];
  const int*   bidx  = (const int*)d_in[1];
  const float* W1 = (const float*)d_in[2];
  const float* g1 = (const float*)d_in[3];
  const float* b1 = (const float*)d_in[4];
  const float* W2 = (const float*)d_in[5];
  const float* g2 = (const float*)d_in[6];
  const float* b2 = (const float*)d_in[7];
  const float* W3 = (const float*)d_in[8];
  const float* b3 = (const float*)d_in[9];
  float* wsf = (float*)d_ws;
  float* out = (float*)d_out;
  (void)hipMemsetAsync(d_ws, 0, 4112*sizeof(float), stream);
  kA<<<256, 256, 0, stream>>>(feats, bidx, wsf);
  kC<<<1024,256, 0, stream>>>(feats, bidx, W1, wsf);
  kB<<<1,   256, 0, stream>>>(wsf, W1,g1,b1, W2,g2,b2, W3);
  kF<<<1024,256, 0, stream>>>(feats, bidx, wsf, b3, out);
}

// Round 3
// 101.232 us; speedup vs baseline: 1.7854x; 1.7854x over previous
//
#include <hip/hip_runtime.h>
#include <hip/hip_bf16.h>

#define EPS 1e-5f
#define NPTS 262144
#define NB 16
#define ACBLK 256

typedef __attribute__((ext_vector_type(8))) short bf16x8;
typedef __attribute__((ext_vector_type(4))) float f32x4;

// ws float/u32 offsets
#define WS_E    0       // 192 f: E'0[64],E'1[64],E'2[64]
#define WS_T    192     // 1024 f: T''[16][64]
#define WS_W3   1216    // 2048 u32 = 4096 bf16 (W3 row-major [64][64])
#define WS_MAXG 3264    // 2048 u32 fallback merged maxima (memset 0)
#define WS_SCRM 5312    // 256*73 f per-block moments(9)+hist(64)
#define WS_PART 24000   // 16*2048 u32 kM partial maxima
#define WS_SMAX 56768   // 256*2048 u32 per-block maxima

__device__ inline float decodeu(unsigned u){
  unsigned bits = (u & 0x80000000u) ? (u ^ 0x80000000u) : ~u;
  return __uint_as_float(bits);
}
__device__ inline unsigned f2bf(float f){
  unsigned u = __float_as_uint(f);
  return (u + 0x7FFFu + ((u>>16)&1u)) >> 16;
}
__device__ inline unsigned pack2bf(float lo, float hi){
  return (f2bf(hi)<<16) | (f2bf(lo) & 0xFFFFu);
}

// ---- kAC: fused moments + per-batch directional max of feats@W1'^T ----
// 256 blocks x 512 thr. Block owns 1024 points. 8 waves = 4 point-quarters
// x 2 channel-halves. Even waves also accumulate moments + batch hist.
__global__ __launch_bounds__(512) void kAC(const float* __restrict__ feats,
                                           const int* __restrict__ bidx,
                                           const float* __restrict__ W1,
                                           const float* __restrict__ g1,
                                           float* __restrict__ wsf, int mode) {
  __shared__ unsigned lmax[NB*128];
  __shared__ float hist[NB*4];
  __shared__ float red[4*9];
  int tid = threadIdx.x;
  for (int i=tid;i<NB*128;i+=512) lmax[i]=0u;
  if (tid < NB*4) hist[tid]=0.f;
  int lane = tid&63, wv = tid>>6;
  int c = (wv&1)*64 + lane;
  float sgn = (g1[c]>=0.f)?1.f:-1.f;   // fold sign(gamma1) into direction
  float w0=W1[3*c]*sgn, w1=W1[3*c+1]*sgn, w2=W1[3*c+2]*sgn;
  bool momdut = (wv&1)==0;
  float a0=0,a1=0,a2=0,a3=0,a4=0,a5=0,a6=0,a7=0,a8=0;
  __syncthreads();
  int base0 = blockIdx.x*1024 + (wv>>1)*256;
  for (int t=0;t<4;t++){
    int p = base0 + t*64 + lane;
    float pf0=feats[3*p], pf1=feats[3*p+1], pf2=feats[3*p+2];
    int pb = bidx[p];
    if (momdut){
      a0+=pf0; a1+=pf1; a2+=pf2;
      a3+=pf0*pf0; a4+=pf0*pf1; a5+=pf0*pf2;
      a6+=pf1*pf1; a7+=pf1*pf2; a8+=pf2*pf2;
      atomicAdd(&hist[pb*4+0],pf0);
      atomicAdd(&hist[pb*4+1],pf1);
      atomicAdd(&hist[pb*4+2],pf2);
      atomicAdd(&hist[pb*4+3],1.0f);
    }
    #pragma unroll
    for (int k=0;k<64;k++){
      float sf0=__uint_as_float(__builtin_amdgcn_readlane(__float_as_uint(pf0),k));
      float sf1=__uint_as_float(__builtin_amdgcn_readlane(__float_as_uint(pf1),k));
      float sf2=__uint_as_float(__builtin_amdgcn_readlane(__float_as_uint(pf2),k));
      int sb=__builtin_amdgcn_readlane(pb,k);
      float v=fmaf(sf2,w2,fmaf(sf1,w1,sf0*w0));
      unsigned bits=__float_as_uint(v);
      unsigned u=((int)bits<0)?~bits:(bits|0x80000000u);
      atomicMax(&lmax[sb*128+c],u);
    }
  }
  if (momdut){
    float acc[9]={a0,a1,a2,a3,a4,a5,a6,a7,a8};
    #pragma unroll
    for (int k=0;k<9;k++){
      float v=acc[k];
      v+=__shfl_down(v,32); v+=__shfl_down(v,16); v+=__shfl_down(v,8);
      v+=__shfl_down(v,4);  v+=__shfl_down(v,2);  v+=__shfl_down(v,1);
      if (lane==0) red[(wv>>1)*9+k]=v;
    }
  }
  __syncthreads();
  float* scrM = wsf + WS_SCRM + blockIdx.x*73;
  if (tid<9) scrM[tid]=red[tid]+red[9+tid]+red[18+tid]+red[27+tid];
  if (tid>=64 && tid<128) scrM[9+tid-64]=hist[tid-64];
  if (mode){
    unsigned* sp = (unsigned*)wsf + WS_SMAX + blockIdx.x*2048;
    for (int i=tid;i<2048;i+=512) sp[i]=lmax[i];
  } else {
    unsigned* mg = (unsigned*)wsf + WS_MAXG;
    for (int i=tid;i<2048;i+=512){ unsigned v=lmax[i]; if(v) atomicMax(&mg[i],v); }
  }
}

// ---- kM: tree-merge per-block maxima: 256 blocks -> 16 partials ----
__global__ __launch_bounds__(256) void kM(float* __restrict__ wsf){
  int g = blockIdx.x >> 3, ec = blockIdx.x & 7;
  int e = ec*256 + threadIdx.x;
  const unsigned* smax = (const unsigned*)wsf + WS_SMAX;
  unsigned m = 0;
  #pragma unroll 4
  for (int k=g*16;k<g*16+16;k++){ unsigned t=smax[(size_t)k*2048+e]; m = t>m?t:m; }
  ((unsigned*)wsf)[WS_PART + g*2048 + e] = m;
}

// ---- kB: all tiny math (single block) ----
__global__ __launch_bounds__(256) void kB(float* __restrict__ wsf,
    const float* __restrict__ W1, const float* __restrict__ g1, const float* __restrict__ b1,
    const float* __restrict__ W2, const float* __restrict__ g2, const float* __restrict__ b2,
    const float* __restrict__ W3, int mode) {
  __shared__ float s_sc[128], s_sh[128], s_smbn[NB*128], sE[3*64], sg[64], sT[NB*64];
  __shared__ float smom[80], s_s2[64], s_t2[64];
  int tid = threadIdx.x;
  if (tid<73){
    float s=0; const float* sm0 = wsf + WS_SCRM;
    for (int k=0;k<ACBLK;k++) s += sm0[k*73+tid];
    smom[tid]=s;
  }
  __syncthreads();
  const float invN = 1.0f/NPTS;
  if (tid < 128){
    int c=tid; float w0=W1[3*c],w1=W1[3*c+1],w2=W1[3*c+2];
    float mean = (w0*smom[0]+w1*smom[1]+w2*smom[2])*invN;
    float ex2 = (w0*w0*smom[3]+w1*w1*smom[6]+w2*w2*smom[8]
               + 2.f*(w0*w1*smom[4]+w0*w2*smom[5]+w1*w2*smom[7]))*invN;
    float var = ex2 - mean*mean;
    float sc = g1[c]*rsqrtf(var+EPS);
    s_sc[c]=sc; s_sh[c]=b1[c]-mean*sc;
  }
  __syncthreads();
  { const unsigned* part=(const unsigned*)wsf+WS_PART;
    const unsigned* mg=(const unsigned*)wsf+WS_MAXG;
    for (int i=tid;i<NB*128;i+=256){
      unsigned u;
      if (mode){ u=0;
        #pragma unroll
        for (int g=0;g<16;g++){ unsigned t=part[g*2048+i]; u = t>u?t:u; }
      } else u = mg[i];
      float M = decodeu(u);               // = max of sign(g1)*v
      int ch=i&127;
      s_smbn[i] = fabsf(s_sc[ch])*M + s_sh[ch];
    } }
  __syncthreads();
  { int c = tid & 63, which = tid >> 6;
    float s=0;
    for (int j=0;j<128;j++){
      float m = (which<3) ? s_sc[j]*W1[3*j+which] : s_sh[j];
      s += W2[c*256+j]*m;
    }
    if (which<3) sE[which*64+c]=s; else sg[c]=s; }
  __syncthreads();
  for (int i=tid;i<NB*64;i+=256){
    int b=i>>6, c=i&63; float s=0;
    for (int j=0;j<128;j++) s += W2[c*256+128+j]*s_smbn[b*128+j];
    sT[i]=s;
  }
  __syncthreads();
  if (tid < 64){
    int c=tid;
    float e0=sE[c],e1=sE[64+c],e2=sE[128+c],gc=sg[c];
    float sumY = e0*smom[0]+e1*smom[1]+e2*smom[2];
    float sumYY = e0*e0*smom[3]+e1*e1*smom[6]+e2*e2*smom[8]
               + 2.f*(e0*e1*smom[4]+e0*e2*smom[5]+e1*e2*smom[7]);
    #pragma unroll
    for (int b=0;b<NB;b++){
      float nb = smom[9+b*4+3];
      float hb = gc + sT[b*64+c];
      float eS1b = e0*smom[9+b*4]+e1*smom[9+b*4+1]+e2*smom[9+b*4+2];
      sumY += nb*hb;
      sumYY += 2.f*hb*eS1b + nb*hb*hb;
    }
    float mean2 = sumY*invN;
    float var2 = sumYY*invN - mean2*mean2;
    float s2 = g2[c]*rsqrtf(var2+EPS);
    float t2 = b2[c]-mean2*s2;
    s_s2[c]=s2; s_t2[c]=t2;
    wsf[WS_E + c] = e0*s2; wsf[WS_E+64+c]=e1*s2; wsf[WS_E+128+c]=e2*s2;
  }
  __syncthreads();
  for (int i=tid;i<NB*64;i+=256){
    int c=i&63;
    wsf[WS_T + i] = (sg[c]+sT[i])*s_s2[c] + s_t2[c];
  }
  { unsigned* w3u = (unsigned*)wsf + WS_W3;
    for (int i=tid;i<2048;i+=256){
      int k=i>>5, cp=i&31;
      w3u[i] = pack2bf(W3[k*64+2*cp], W3[k*64+2*cp+1]);
    } }
}

// ---- kF: fused y2 -> bn2/relu -> z@W3.T + b3 ----
__global__ __launch_bounds__(256) void kF(const float* __restrict__ feats,
                                          const int* __restrict__ bidx,
                                          const float* __restrict__ wsf,
                                          const float* __restrict__ b3,
                                          float* __restrict__ out) {
  __shared__ __align__(16) float Tl[NB*66];
  __shared__ __align__(16) unsigned zbuf[4*64*32];   // 4 waves x 64 rows x 128B
  int tid = threadIdx.x;
  for (int i=tid;i<NB*64;i+=256) Tl[(i>>6)*66 + (i&63)] = wsf[WS_T + i];
  int lane = tid & 63, wv = tid >> 6;
  int col = lane & 15, kgrp = lane >> 4;
  const ushort* w3b = (const ushort*)((const unsigned*)wsf + WS_W3);
  bf16x8 bfr[4][2];
  #pragma unroll
  for (int n=0;n<4;n++)
    #pragma unroll
    for (int kk=0;kk<2;kk++)
      bfr[n][kk] = *(const bf16x8*)(w3b + (n*16+col)*64 + kk*32 + kgrp*8);
  float bias[4];
  #pragma unroll
  for (int n=0;n<4;n++) bias[n] = b3[n*16+col];
  __syncthreads();
  const float* Eg = wsf + WS_E;
  int p0 = (blockIdx.x*4 + wv)*64;
  int p = p0 + lane;
  float f0 = feats[3*p], f1 = feats[3*p+1], f2 = feats[3*p+2];
  int b = bidx[p];
  const float* tb = &Tl[b*66];
  unsigned rowbase = (unsigned)(wv*64+lane)*32;
  unsigned sw = (lane&7)<<2;
  #pragma unroll
  for (int j=0;j<8;j++){
    unsigned w[4];
    #pragma unroll
    for (int q=0;q<4;q++){
      int c = j*8 + q*2;
      float2 tp = *(const float2*)(tb + c);
      float y0 = fmaf(Eg[c],  f0, fmaf(Eg[64+c],  f1, fmaf(Eg[128+c],  f2, tp.x)));
      float y1 = fmaf(Eg[c+1],f0, fmaf(Eg[64+c+1],f1, fmaf(Eg[128+c+1],f2, tp.y)));
      w[q] = pack2bf(fmaxf(y0,0.f), fmaxf(y1,0.f));
    }
    uint4 ch; ch.x=w[0]; ch.y=w[1]; ch.z=w[2]; ch.w=w[3];
    *(uint4*)&zbuf[rowbase + (((unsigned)(j*4)) ^ sw)] = ch;
  }
  __syncthreads();
  bf16x8 af[4][2];
  #pragma unroll
  for (int m=0;m<4;m++){
    int row = m*16 + col;
    unsigned rb = (unsigned)(wv*64+row)*32;
    unsigned sw2 = (unsigned)(row&7)<<2;
    #pragma unroll
    for (int kk=0;kk<2;kk++){
      unsigned off = ((unsigned)(kk*16 + kgrp*4)) ^ sw2;
      af[m][kk] = *(const bf16x8*)&zbuf[rb + off];
    }
  }
  f32x4 acc[4][4];
  #pragma unroll
  for (int m=0;m<4;m++)
    #pragma unroll
    for (int n=0;n<4;n++)
      acc[m][n] = (f32x4){0.f,0.f,0.f,0.f};
  #pragma unroll
  for (int kk=0;kk<2;kk++)
    #pragma unroll
    for (int m=0;m<4;m++)
      #pragma unroll
      for (int n=0;n<4;n++)
        acc[m][n] = __builtin_amdgcn_mfma_f32_16x16x32_bf16(af[m][kk], bfr[n][kk], acc[m][n], 0,0,0);
  #pragma unroll
  for (int m=0;m<4;m++){
    int prow = p0 + m*16 + kgrp*4;
    #pragma unroll
    for (int n=0;n<4;n++){
      int cg = n*16+col;
      #pragma unroll
      for (int r=0;r<4;r++)
        out[(size_t)(prow+r)*64 + cg] = acc[m][n][r] + bias[n];
    }
  }
}

extern "C" void kernel_launch(void* const* d_in, const int* in_sizes, int n_in,
                              void* d_out, int out_size, void* d_ws, size_t ws_size,
                              hipStream_t stream) {
  const float* feats = (const float*)d_in[0];
  const int*   bidx  = (const int*)d_in[1];
  const float* W1 = (const float*)d_in[2];
  const float* g1 = (const float*)d_in[3];
  const float* b1 = (const float*)d_in[4];
  const float* W2 = (const float*)d_in[5];
  const float* g2 = (const float*)d_in[6];
  const float* b2 = (const float*)d_in[7];
  const float* W3 = (const float*)d_in[8];
  const float* b3 = (const float*)d_in[9];
  float* wsf = (float*)d_ws;
  float* out = (float*)d_out;
  size_t need = (size_t)(WS_SMAX + ACBLK*2048)*4;
  int mode = (ws_size >= need) ? 1 : 0;
  (void)hipMemsetAsync((char*)d_ws + (size_t)WS_MAXG*4, 0, 2048*4, stream);
  kAC<<<ACBLK, 512, 0, stream>>>(feats, bidx, W1, g1, wsf, mode);
  if (mode) kM<<<128, 256, 0, stream>>>(wsf);
  kB<<<1, 256, 0, stream>>>(wsf, W1,g1,b1, W2,g2,b2, W3, mode);
  kF<<<1024, 256, 0, stream>>>(feats, bidx, wsf, b3, out);
}

// Round 4
// 75.921 us; speedup vs baseline: 2.3806x; 1.3334x over previous
//
#include <hip/hip_runtime.h>
#include <hip/hip_bf16.h>

#define EPS 1e-5f
#define NPTS 262144
#define NB 16
#define ACBLK 256

typedef __attribute__((ext_vector_type(8))) short bf16x8;
typedef __attribute__((ext_vector_type(4))) float f32x4;

// ws float/u32 offsets
#define WS_E    0        // 192 f
#define WS_T    192      // 1024 f
#define WS_W3   1216     // 2048 u32
#define WS_MAXG 3264     // 2048 u32 fallback merged maxima (memset 0 in mode 0)
#define WS_PMOM 5312     // 16*73 f kM partial moments
#define WS_SCRM 6480     // 256*73 f per-block moments(9)+hist(64)
#define WS_PART 25168    // 16*2048 u32 kM partial maxima
#define WS_SMAX 57936    // 256*2048 u32 per-block maxima

__device__ inline float decodeu(unsigned u){
  unsigned bits = (u & 0x80000000u) ? (u ^ 0x80000000u) : ~u;
  return __uint_as_float(bits);
}
__device__ inline unsigned f2bf(float f){
  unsigned u = __float_as_uint(f);
  return (u + 0x7FFFu + ((u>>16)&1u)) >> 16;
}
__device__ inline unsigned pack2bf(float lo, float hi){
  return (f2bf(hi)<<16) | (f2bf(lo) & 0xFFFFu);
}

// ---- kAC: fused moments + per-batch directional max of feats@W1'^T ----
__global__ __launch_bounds__(512) void kAC(const float* __restrict__ feats,
                                           const int* __restrict__ bidx,
                                           const float* __restrict__ W1,
                                           const float* __restrict__ g1,
                                           float* __restrict__ wsf, int mode) {
  __shared__ unsigned lmax[NB*128];
  __shared__ float hist[NB*4];
  __shared__ float red[4*9];
  int tid = threadIdx.x;
  for (int i=tid;i<NB*128;i+=512) lmax[i]=0u;
  if (tid < NB*4) hist[tid]=0.f;
  int lane = tid&63, wv = tid>>6;
  int c = (wv&1)*64 + lane;
  float sgn = (g1[c]>=0.f)?1.f:-1.f;   // fold sign(gamma1) into direction
  float w0=W1[3*c]*sgn, w1=W1[3*c+1]*sgn, w2=W1[3*c+2]*sgn;
  bool momdut = (wv&1)==0;
  float a0=0,a1=0,a2=0,a3=0,a4=0,a5=0,a6=0,a7=0,a8=0;
  __syncthreads();
  int base0 = blockIdx.x*1024 + (wv>>1)*256;
  for (int t=0;t<4;t++){
    int p = base0 + t*64 + lane;
    float pf0=feats[3*p], pf1=feats[3*p+1], pf2=feats[3*p+2];
    int pb = bidx[p];
    if (momdut){
      a0+=pf0; a1+=pf1; a2+=pf2;
      a3+=pf0*pf0; a4+=pf0*pf1; a5+=pf0*pf2;
      a6+=pf1*pf1; a7+=pf1*pf2; a8+=pf2*pf2;
      atomicAdd(&hist[pb*4+0],pf0);
      atomicAdd(&hist[pb*4+1],pf1);
      atomicAdd(&hist[pb*4+2],pf2);
      atomicAdd(&hist[pb*4+3],1.0f);
    }
    #pragma unroll
    for (int k=0;k<64;k++){
      float sf0=__uint_as_float(__builtin_amdgcn_readlane(__float_as_uint(pf0),k));
      float sf1=__uint_as_float(__builtin_amdgcn_readlane(__float_as_uint(pf1),k));
      float sf2=__uint_as_float(__builtin_amdgcn_readlane(__float_as_uint(pf2),k));
      int sb=__builtin_amdgcn_readlane(pb,k);
      float v=fmaf(sf2,w2,fmaf(sf1,w1,sf0*w0));
      unsigned bits=__float_as_uint(v);
      unsigned u=((int)bits<0)?~bits:(bits|0x80000000u);
      atomicMax(&lmax[sb*128+c],u);
    }
  }
  if (momdut){
    float acc[9]={a0,a1,a2,a3,a4,a5,a6,a7,a8};
    #pragma unroll
    for (int k=0;k<9;k++){
      float v=acc[k];
      v+=__shfl_down(v,32); v+=__shfl_down(v,16); v+=__shfl_down(v,8);
      v+=__shfl_down(v,4);  v+=__shfl_down(v,2);  v+=__shfl_down(v,1);
      if (lane==0) red[(wv>>1)*9+k]=v;
    }
  }
  __syncthreads();
  float* scrM = wsf + WS_SCRM + blockIdx.x*73;
  if (tid<9) scrM[tid]=red[tid]+red[9+tid]+red[18+tid]+red[27+tid];
  if (tid>=64 && tid<128) scrM[9+tid-64]=hist[tid-64];
  if (mode){
    unsigned* sp = (unsigned*)wsf + WS_SMAX + blockIdx.x*2048;
    for (int i=tid;i<2048;i+=512) sp[i]=lmax[i];
  } else {
    unsigned* mg = (unsigned*)wsf + WS_MAXG;
    for (int i=tid;i<2048;i+=512){ unsigned v=lmax[i]; if(v) atomicMax(&mg[i],v); }
  }
}

// ---- kM: tree-merge per-block maxima 256->16, moments 256->16 ----
__global__ __launch_bounds__(256) void kM(float* __restrict__ wsf){
  int g = blockIdx.x >> 3, ec = blockIdx.x & 7;
  int e = ec*256 + threadIdx.x;
  const unsigned* smax = (const unsigned*)wsf + WS_SMAX;
  unsigned m = 0;
  #pragma unroll 4
  for (int k=g*16;k<g*16+16;k++){ unsigned t=smax[(size_t)k*2048+e]; m = t>m?t:m; }
  ((unsigned*)wsf)[WS_PART + g*2048 + e] = m;
  if (ec==0 && threadIdx.x<73){
    float s=0; const float* sm0 = wsf + WS_SCRM;
    #pragma unroll 4
    for (int k=g*16;k<g*16+16;k++) s += sm0[k*73+threadIdx.x];
    wsf[WS_PMOM + g*73 + threadIdx.x] = s;
  }
}

// ---- kB: all tiny math (single block, LDS-staged) ----
__global__ __launch_bounds__(256) void kB(float* __restrict__ wsf,
    const float* __restrict__ W1, const float* __restrict__ g1, const float* __restrict__ b1,
    const float* __restrict__ W2, const float* __restrict__ g2, const float* __restrict__ b2,
    const float* __restrict__ W3, int mode) {
  __shared__ float w2t[256*66];     // W2 transposed [j][c], pad 66
  __shared__ float s_w1[384];
  __shared__ float s_sc[128], s_sh[128], s_smbn[NB*128], sE[3*64], sg[64], sT[NB*64];
  __shared__ float smom[80], s_s2[64], s_t2[64];
  int tid = threadIdx.x;
  // phase 1: stage W2 (coalesced global, 2-way-bank LDS write), W1, moments, W3 pack
  for (int i=tid;i<16384;i+=256){ int c=i>>8, j=i&255; w2t[j*66+c]=W2[i]; }
  for (int i=tid;i<384;i+=256) s_w1[i]=W1[i];
  if (mode){
    if (tid<73){ float s=0;
      #pragma unroll
      for (int g=0;g<16;g++) s += wsf[WS_PMOM+g*73+tid];
      smom[tid]=s; }
  } else {
    if (tid<73){ float s=0; const float* sm0=wsf+WS_SCRM;
      for (int k=0;k<ACBLK;k++) s += sm0[k*73+tid];
      smom[tid]=s; }
  }
  { unsigned* w3u = (unsigned*)wsf + WS_W3;
    for (int i=tid;i<2048;i+=256){
      int k=i>>5, cp=i&31;
      w3u[i] = pack2bf(W3[k*64+2*cp], W3[k*64+2*cp+1]);
    } }
  __syncthreads();
  const float invN = 1.0f/NPTS;
  if (tid < 128){
    int c=tid; float w0=s_w1[3*c],w1=s_w1[3*c+1],w2=s_w1[3*c+2];
    float mean = (w0*smom[0]+w1*smom[1]+w2*smom[2])*invN;
    float ex2 = (w0*w0*smom[3]+w1*w1*smom[6]+w2*w2*smom[8]
               + 2.f*(w0*w1*smom[4]+w0*w2*smom[5]+w1*w2*smom[7]))*invN;
    float var = ex2 - mean*mean;
    float sc = g1[c]*rsqrtf(var+EPS);
    s_sc[c]=sc; s_sh[c]=b1[c]-mean*sc;
  }
  __syncthreads();
  { const unsigned* part=(const unsigned*)wsf+WS_PART;
    const unsigned* mg=(const unsigned*)wsf+WS_MAXG;
    for (int i=tid;i<NB*128;i+=256){
      unsigned u;
      if (mode){ u=0;
        #pragma unroll
        for (int g=0;g<16;g++){ unsigned t=part[g*2048+i]; u = t>u?t:u; }
      } else u = mg[i];
      float M = decodeu(u);               // = max over batch of sign(g1)*y1
      int ch=i&127;
      s_smbn[i] = fabsf(s_sc[ch])*M + s_sh[ch];
    } }
  __syncthreads();
  { int c = tid & 63, which = tid >> 6;
    float s=0;
    for (int j=0;j<128;j++){
      float m = (which<3) ? s_sc[j]*s_w1[3*j+which] : s_sh[j];
      s += w2t[j*66+c]*m;
    }
    if (which<3) sE[which*64+c]=s; else sg[c]=s; }
  for (int i=tid;i<NB*64;i+=256){
    int b=i>>6, c=i&63; float s=0;
    for (int j=0;j<128;j++) s += w2t[(128+j)*66+c]*s_smbn[b*128+j];
    sT[i]=s;
  }
  __syncthreads();
  if (tid < 64){
    int c=tid;
    float e0=sE[c],e1=sE[64+c],e2=sE[128+c],gc=sg[c];
    float sumY = e0*smom[0]+e1*smom[1]+e2*smom[2];
    float sumYY = e0*e0*smom[3]+e1*e1*smom[6]+e2*e2*smom[8]
               + 2.f*(e0*e1*smom[4]+e0*e2*smom[5]+e1*e2*smom[7]);
    #pragma unroll
    for (int b=0;b<NB;b++){
      float nb = smom[9+b*4+3];
      float hb = gc + sT[b*64+c];
      float eS1b = e0*smom[9+b*4]+e1*smom[9+b*4+1]+e2*smom[9+b*4+2];
      sumY += nb*hb;
      sumYY += 2.f*hb*eS1b + nb*hb*hb;
    }
    float mean2 = sumY*invN;
    float var2 = sumYY*invN - mean2*mean2;
    float s2 = g2[c]*rsqrtf(var2+EPS);
    float t2 = b2[c]-mean2*s2;
    s_s2[c]=s2; s_t2[c]=t2;
    wsf[WS_E + c] = e0*s2; wsf[WS_E+64+c]=e1*s2; wsf[WS_E+128+c]=e2*s2;
  }
  __syncthreads();
  for (int i=tid;i<NB*64;i+=256){
    int c=i&63;
    wsf[WS_T + i] = (sg[c]+sT[i])*s_s2[c] + s_t2[c];
  }
}

// ---- kF: fused y2 -> bn2/relu -> z@W3.T + b3 ----
__global__ __launch_bounds__(256) void kF(const float* __restrict__ feats,
                                          const int* __restrict__ bidx,
                                          const float* __restrict__ wsf,
                                          const float* __restrict__ b3,
                                          float* __restrict__ out) {
  __shared__ __align__(16) float Tl[NB*66];
  __shared__ __align__(16) unsigned zbuf[4*64*32];   // 4 waves x 64 rows x 128B
  int tid = threadIdx.x;
  for (int i=tid;i<NB*64;i+=256) Tl[(i>>6)*66 + (i&63)] = wsf[WS_T + i];
  int lane = tid & 63, wv = tid >> 6;
  int col = lane & 15, kgrp = lane >> 4;
  const ushort* w3b = (const ushort*)((const unsigned*)wsf + WS_W3);
  bf16x8 bfr[4][2];
  #pragma unroll
  for (int n=0;n<4;n++)
    #pragma unroll
    for (int kk=0;kk<2;kk++)
      bfr[n][kk] = *(const bf16x8*)(w3b + (n*16+col)*64 + kk*32 + kgrp*8);
  float bias[4];
  #pragma unroll
  for (int n=0;n<4;n++) bias[n] = b3[n*16+col];
  __syncthreads();
  const float* Eg = wsf + WS_E;
  int p0 = (blockIdx.x*4 + wv)*64;
  int p = p0 + lane;
  float f0 = feats[3*p], f1 = feats[3*p+1], f2 = feats[3*p+2];
  int b = bidx[p];
  const float* tb = &Tl[b*66];
  unsigned rowbase = (unsigned)(wv*64+lane)*32;
  unsigned sw = (lane&7)<<2;
  #pragma unroll
  for (int j=0;j<8;j++){
    unsigned w[4];
    #pragma unroll
    for (int q=0;q<4;q++){
      int c = j*8 + q*2;
      float2 tp = *(const float2*)(tb + c);
      float y0 = fmaf(Eg[c],  f0, fmaf(Eg[64+c],  f1, fmaf(Eg[128+c],  f2, tp.x)));
      float y1 = fmaf(Eg[c+1],f0, fmaf(Eg[64+c+1],f1, fmaf(Eg[128+c+1],f2, tp.y)));
      w[q] = pack2bf(fmaxf(y0,0.f), fmaxf(y1,0.f));
    }
    uint4 ch; ch.x=w[0]; ch.y=w[1]; ch.z=w[2]; ch.w=w[3];
    *(uint4*)&zbuf[rowbase + (((unsigned)(j*4)) ^ sw)] = ch;
  }
  __syncthreads();
  bf16x8 af[4][2];
  #pragma unroll
  for (int m=0;m<4;m++){
    int row = m*16 + col;
    unsigned rb = (unsigned)(wv*64+row)*32;
    unsigned sw2 = (unsigned)(row&7)<<2;
    #pragma unroll
    for (int kk=0;kk<2;kk++){
      unsigned off = ((unsigned)(kk*16 + kgrp*4)) ^ sw2;
      af[m][kk] = *(const bf16x8*)&zbuf[rb + off];
    }
  }
  f32x4 acc[4][4];
  #pragma unroll
  for (int m=0;m<4;m++)
    #pragma unroll
    for (int n=0;n<4;n++)
      acc[m][n] = (f32x4){0.f,0.f,0.f,0.f};
  #pragma unroll
  for (int kk=0;kk<2;kk++)
    #pragma unroll
    for (int m=0;m<4;m++)
      #pragma unroll
      for (int n=0;n<4;n++)
        acc[m][n] = __builtin_amdgcn_mfma_f32_16x16x32_bf16(af[m][kk], bfr[n][kk], acc[m][n], 0,0,0);
  #pragma unroll
  for (int m=0;m<4;m++){
    int prow = p0 + m*16 + kgrp*4;
    #pragma unroll
    for (int n=0;n<4;n++){
      int cg = n*16+col;
      #pragma unroll
      for (int r=0;r<4;r++)
        out[(size_t)(prow+r)*64 + cg] = acc[m][n][r] + bias[n];
    }
  }
}

extern "C" void kernel_launch(void* const* d_in, const int* in_sizes, int n_in,
                              void* d_out, int out_size, void* d_ws, size_t ws_size,
                              hipStream_t stream) {
  const float* feats = (const float*)d_in[0];
  const int*   bidx  = (const int*)d_in[1];
  const float* W1 = (const float*)d_in[2];
  const float* g1 = (const float*)d_in[3];
  const float* b1 = (const float*)d_in[4];
  const float* W2 = (const float*)d_in[5];
  const float* g2 = (const float*)d_in[6];
  const float* b2 = (const float*)d_in[7];
  const float* W3 = (const float*)d_in[8];
  const float* b3 = (const float*)d_in[9];
  float* wsf = (float*)d_ws;
  float* out = (float*)d_out;
  size_t need = (size_t)(WS_SMAX + ACBLK*2048)*4;
  int mode = (ws_size >= need) ? 1 : 0;
  if (!mode) (void)hipMemsetAsync((char*)d_ws + (size_t)WS_MAXG*4, 0, 2048*4, stream);
  kAC<<<ACBLK, 512, 0, stream>>>(feats, bidx, W1, g1, wsf, mode);
  if (mode) kM<<<128, 256, 0, stream>>>(wsf);
  kB<<<1, 256, 0, stream>>>(wsf, W1,g1,b1, W2,g2,b2, W3, mode);
  kF<<<1024, 256, 0, stream>>>(feats, bidx, wsf, b3, out);
}